// Round 1
// baseline (155.860 us; speedup 1.0000x reference)
//
#include <hip/hip_runtime.h>

// NegLogLikelihood:
//   mean, cov = split(output, 2, axis=0)   each [4096, 2048] fp32
//   logdet = sum(log(cov))                 scalar
//   out = -((mean - target)^2 / cov + logdet)
//
// Two-phase: (1) reduce logdet into d_ws[0], (2) elementwise map.

#define N_ELEMS (4096 * 2048)      // per-half element count
#define N_VEC4  (N_ELEMS / 4)

__global__ __launch_bounds__(256) void logdet_reduce_kernel(
    const float* __restrict__ cov, float* __restrict__ accum, int n4) {
    const float4* __restrict__ c4 = reinterpret_cast<const float4*>(cov);
    int idx = blockIdx.x * blockDim.x + threadIdx.x;
    int stride = gridDim.x * blockDim.x;

    float s = 0.0f;
    for (int i = idx; i < n4; i += stride) {
        float4 v = c4[i];
        s += __logf(v.x) + __logf(v.y) + __logf(v.z) + __logf(v.w);
    }

    // wave (64-lane) reduction
    #pragma unroll
    for (int off = 32; off > 0; off >>= 1)
        s += __shfl_down(s, off, 64);

    // block reduction across 4 waves
    __shared__ float wsum[4];
    int lane = threadIdx.x & 63;
    int wave = threadIdx.x >> 6;
    if (lane == 0) wsum[wave] = s;
    __syncthreads();
    if (threadIdx.x == 0) {
        float b = wsum[0] + wsum[1] + wsum[2] + wsum[3];
        atomicAdd(accum, b);   // device-scope by default on CDNA
    }
}

__global__ __launch_bounds__(256) void nll_elem_kernel(
    const float* __restrict__ mean, const float* __restrict__ cov,
    const float* __restrict__ target, const float* __restrict__ logdet_p,
    float* __restrict__ out, int n4) {
    const float4* __restrict__ m4 = reinterpret_cast<const float4*>(mean);
    const float4* __restrict__ c4 = reinterpret_cast<const float4*>(cov);
    const float4* __restrict__ t4 = reinterpret_cast<const float4*>(target);
    float4* __restrict__ o4 = reinterpret_cast<float4*>(out);

    const float logdet = *logdet_p;   // scalar broadcast (L2 hit)

    int idx = blockIdx.x * blockDim.x + threadIdx.x;
    int stride = gridDim.x * blockDim.x;

    for (int i = idx; i < n4; i += stride) {
        float4 m = m4[i];
        float4 c = c4[i];
        float4 t = t4[i];
        float4 r;
        float ex = m.x - t.x;
        float ey = m.y - t.y;
        float ez = m.z - t.z;
        float ew = m.w - t.w;
        r.x = -(ex * ex / c.x + logdet);
        r.y = -(ey * ey / c.y + logdet);
        r.z = -(ez * ez / c.z + logdet);
        r.w = -(ew * ew / c.w + logdet);
        o4[i] = r;
    }
}

extern "C" void kernel_launch(void* const* d_in, const int* in_sizes, int n_in,
                              void* d_out, int out_size, void* d_ws, size_t ws_size,
                              hipStream_t stream) {
    const float* output = (const float*)d_in[0];   // [8192, 2048]
    const float* target = (const float*)d_in[1];   // [4096, 2048]
    const float* mean = output;
    const float* cov  = output + N_ELEMS;
    float* out = (float*)d_out;
    float* accum = (float*)d_ws;

    // zero the logdet accumulator (d_ws is poisoned 0xAA before every launch)
    hipMemsetAsync(accum, 0, sizeof(float), stream);

    const int threads = 256;
    const int blocks = 2048;   // 256 CUs x 8 blocks, grid-stride

    logdet_reduce_kernel<<<blocks, threads, 0, stream>>>(cov, accum, N_VEC4);
    nll_elem_kernel<<<blocks, threads, 0, stream>>>(mean, cov, target, accum, out, N_VEC4);
}

// Round 2
// 132.079 us; speedup vs baseline: 1.1801x; 1.1801x over previous
//
#include <hip/hip_runtime.h>

// NegLogLikelihood:
//   mean, cov = split(output, 2, axis=0)   each [4096, 2048] fp32
//   logdet = sum(log(cov))                 scalar
//   out = -((mean - target)^2 / cov + logdet)
//
// Two-node graph (no memset, no atomics):
//   k1: per-block log-sum partials -> d_ws[0..2047]
//   k2: block-redundant reduce of partials + elementwise map

#define N_ELEMS (4096 * 2048)      // per-half element count
#define N_VEC4  (N_ELEMS / 4)      // 2097152 float4s
#define NBLK    2048
#define NTHR    256
#define ITERS   (N_VEC4 / (NBLK * NTHR))   // 4

__global__ __launch_bounds__(256) void logdet_partial_kernel(
    const float* __restrict__ cov, float* __restrict__ partials) {
    const float4* __restrict__ c4 = reinterpret_cast<const float4*>(cov);
    int idx = blockIdx.x * blockDim.x + threadIdx.x;
    const int stride = NBLK * NTHR;

    float s = 0.0f;
    #pragma unroll
    for (int it = 0; it < ITERS; ++it) {
        float4 v = c4[idx + it * stride];
        s += __logf(v.x) + __logf(v.y) + __logf(v.z) + __logf(v.w);
    }

    // wave (64-lane) reduction
    #pragma unroll
    for (int off = 32; off > 0; off >>= 1)
        s += __shfl_down(s, off, 64);

    __shared__ float wsum[4];
    if ((threadIdx.x & 63) == 0) wsum[threadIdx.x >> 6] = s;
    __syncthreads();
    if (threadIdx.x == 0)
        partials[blockIdx.x] = wsum[0] + wsum[1] + wsum[2] + wsum[3];
}

__global__ __launch_bounds__(256) void nll_elem_kernel(
    const float* __restrict__ mean, const float* __restrict__ cov,
    const float* __restrict__ target, const float* __restrict__ partials,
    float* __restrict__ out) {
    // --- block-redundant reduction of the 2048 partials (8 KB, L2-hot) ---
    const float4* __restrict__ p4 = reinterpret_cast<const float4*>(partials);
    float4 pa = p4[threadIdx.x];
    float4 pb = p4[threadIdx.x + 256];
    float s = (pa.x + pa.y) + (pa.z + pa.w) + (pb.x + pb.y) + (pb.z + pb.w);
    #pragma unroll
    for (int off = 32; off > 0; off >>= 1)
        s += __shfl_down(s, off, 64);
    __shared__ float wsum[4];
    if ((threadIdx.x & 63) == 0) wsum[threadIdx.x >> 6] = s;
    __syncthreads();
    const float logdet = (wsum[0] + wsum[1]) + (wsum[2] + wsum[3]);

    // --- elementwise map ---
    const float4* __restrict__ m4 = reinterpret_cast<const float4*>(mean);
    const float4* __restrict__ c4 = reinterpret_cast<const float4*>(cov);
    const float4* __restrict__ t4 = reinterpret_cast<const float4*>(target);
    float4* __restrict__ o4 = reinterpret_cast<float4*>(out);

    int idx = blockIdx.x * blockDim.x + threadIdx.x;
    const int stride = NBLK * NTHR;

    #pragma unroll
    for (int it = 0; it < ITERS; ++it) {
        int i = idx + it * stride;
        float4 m = m4[i];
        float4 c = c4[i];
        float4 t = t4[i];
        float4 r;
        float ex = m.x - t.x;
        float ey = m.y - t.y;
        float ez = m.z - t.z;
        float ew = m.w - t.w;
        // fast reciprocal (v_rcp_f32, ~1e-7 rel err; term magnitude <= ~20,
        // threshold 1.4e5 -> far within tolerance)
        r.x = -(ex * ex * __builtin_amdgcn_rcpf(c.x) + logdet);
        r.y = -(ey * ey * __builtin_amdgcn_rcpf(c.y) + logdet);
        r.z = -(ez * ez * __builtin_amdgcn_rcpf(c.z) + logdet);
        r.w = -(ew * ew * __builtin_amdgcn_rcpf(c.w) + logdet);
        o4[i] = r;
    }
}

extern "C" void kernel_launch(void* const* d_in, const int* in_sizes, int n_in,
                              void* d_out, int out_size, void* d_ws, size_t ws_size,
                              hipStream_t stream) {
    const float* output = (const float*)d_in[0];   // [8192, 2048]
    const float* target = (const float*)d_in[1];   // [4096, 2048]
    const float* mean = output;
    const float* cov  = output + N_ELEMS;
    float* out = (float*)d_out;
    float* partials = (float*)d_ws;   // 2048 floats; every slot written by k1

    logdet_partial_kernel<<<NBLK, NTHR, 0, stream>>>(cov, partials);
    nll_elem_kernel<<<NBLK, NTHR, 0, stream>>>(mean, cov, target, partials, out);
}